// Round 5
// baseline (227.603 us; speedup 1.0000x reference)
//
#include <hip/hip_runtime.h>

#define NI 100000
#define NJ 50000
#define KD 25
#define SI 8192
#define SJ 4096
#define NE 1000000
#define EPSC 1e-6f
#define LOG2E 1.4426950408889634f
#define HALF_E2 3.6945280494653252f   // 0.5 * e * e

#define NBI ((NI + 255) / 256)   // 391
#define NBJ ((NJ + 255) / 256)   // 196
#define NZI (SI / 64)            // 128
#define NZJ (SJ / 64)            // 64
#define NPKI (SI / 256)          // 32 pack blocks (I)
#define NPKJ (SJ / 256)          // 16 pack blocks (J)
#define NDB 1024                 // dense: 512 row-groups x 2 col-halves
#define NSB 1024                 // sparse
#define NSUMS (NDB + NSB)

// workspace layout (float offsets)
#define W_CSI 0                  // 8 copies x 32
#define W_CSJ 256
#define W_ZCI 512                // 2 copies x 640
#define W_ZCJ 1792
#define W_PART 3072              // 128 partial slots
#define W_CNT 3200               // int completion counter
#define W_QI 4096                // float4[NI]  (x, y, beta, 0)
#define W_QJ (W_QI + 4 * NI)     // float4[NJ]  (x-eps, y-eps, beta, gamma)
#define W_QSI (W_QJ + 4 * NJ)    // float4[SI]  (x, y, e^beta, 0)
#define W_QSJ (W_QSI + 4 * SI)   // float4[SJ]  (x-eps, y-eps, e^gamma, 0)

__device__ __forceinline__ float fexp2(float x) { return __builtin_amdgcn_exp2f(x); }
__device__ __forceinline__ float fsqrt(float x) { return __builtin_amdgcn_sqrtf(x); }
__device__ __forceinline__ float frcp(float x)  { return __builtin_amdgcn_rcpf(x); }
__device__ __forceinline__ float fsig(float g)  { return frcp(1.f + fexp2(-g * LOG2E)); }

__global__ void k_init(float* __restrict__ ws) {
    int t = blockIdx.x * 256 + threadIdx.x;
    if (t < 3328) ws[t] = 0.f;
}

__device__ __forceinline__ void softmax_col(const float* __restrict__ Z, int N, int i,
                                            float* z) {
    float m = -1e30f;
#pragma unroll
    for (int k = 0; k < KD; k++) { z[k] = Z[k * N + i]; m = fmaxf(m, z[k]); }
    float s = 0.f;
#pragma unroll
    for (int k = 0; k < KD; k++) { z[k] = fexp2((z[k] - m) * LOG2E); s += z[k]; }
    float inv = frcp(s);
#pragma unroll
    for (int k = 0; k < KD; k++) z[k] *= inv;
}

// ---- colsum[k] = sum_i softmax(Z)[k,i] * sigmoid(G[i,k]), 8 spread copies ----
// G window for 256 consecutive nodes is contiguous -> stage via LDS, coalesced.
__device__ void colsum_pass(const float* __restrict__ Z, const float* __restrict__ G,
                            float* __restrict__ colsum, int N, int blk) {
    __shared__ float gs[256 * KD];
    int n0 = blk * 256;
    int lim = (N - n0) * KD;
    if (lim > 256 * KD) lim = 256 * KD;
    for (int t = threadIdx.x; t < lim; t += 256) gs[t] = G[n0 * KD + t];
    __syncthreads();
    int i = n0 + threadIdx.x;
    float z[KD];
    if (i < N) {
        softmax_col(Z, N, i, z);
#pragma unroll
        for (int k = 0; k < KD; k++) z[k] *= fsig(gs[threadIdx.x * KD + k]);
    } else {
#pragma unroll
        for (int k = 0; k < KD; k++) z[k] = 0.f;
    }
    __shared__ float part[KD][4];
    int lane = threadIdx.x & 63, wv = threadIdx.x >> 6;
#pragma unroll
    for (int k = 0; k < KD; k++) {
        float v = z[k];
        for (int o = 32; o > 0; o >>= 1) v += __shfl_down(v, o);
        if (lane == 0) part[k][wv] = v;
    }
    __syncthreads();
    if (threadIdx.x < KD) {
        float v = part[threadIdx.x][0] + part[threadIdx.x][1] +
                  part[threadIdx.x][2] + part[threadIdx.x][3];
        atomicAdd(&colsum[((blk & 7) << 5) + threadIdx.x], v);
    }
}

// ---- ZCraw[a,b] = sum_s z[a,s] * (z[b,s]*sig(g[s,b])), 2 spread copies ----
__device__ void zc_pass(const float* __restrict__ Z, const float* __restrict__ G,
                        const int* __restrict__ samp, float* __restrict__ zcraw,
                        int N, int blk) {
    __shared__ float zb[64][KD + 1];
    __shared__ float zs[64][KD + 1];
    int tid = threadIdx.x;
    if (tid < 64) {
        int idx = samp[blk * 64 + tid];
        float z[KD];
        softmax_col(Z, N, idx, z);
#pragma unroll
        for (int k = 0; k < KD; k++) {
            zb[tid][k] = z[k];
            zs[tid][k] = z[k] * fsig(G[idx * KD + k]);
        }
    }
    __syncthreads();
    for (int p = tid; p < KD * KD; p += 256) {
        int a = p / KD, bb = p % KD;
        float acc = 0.f;
#pragma unroll 8
        for (int s = 0; s < 64; s++) acc += zb[s][a] * zs[s][bb];
        atomicAdd(&zcraw[(blk & 1) * 640 + p], acc);
    }
}

__global__ void __launch_bounds__(256) k_s1(const float* __restrict__ Zi,
                                            const float* __restrict__ Zj,
                                            const float* __restrict__ Gi,
                                            const float* __restrict__ Gj,
                                            const int* __restrict__ si,
                                            const int* __restrict__ sj,
                                            float* __restrict__ ws) {
    int b = blockIdx.x;
    if (b < NBI)                  colsum_pass(Zi, Gi, ws + W_CSI, NI, b);
    else if (b < NBI + NBJ)       colsum_pass(Zj, Gj, ws + W_CSJ, NJ, b - NBI);
    else if (b < NBI + NBJ + NZI) zc_pass(Zi, Gi, si, ws + W_ZCI, NI, b - NBI - NBJ);
    else                          zc_pass(Zj, Gj, sj, ws + W_ZCJ, NJ, b - NBI - NBJ - NZI);
}

// ---- per-node points (Qi/Qj) + sampled packed points (QSI/QSJ) ----
__global__ void __launch_bounds__(256) k_pa(const float* __restrict__ Zi,
                                            const float* __restrict__ Zj,
                                            const float* __restrict__ beta,
                                            const float* __restrict__ gamma,
                                            const float* __restrict__ Ai,
                                            const float* __restrict__ Aj,
                                            const int* __restrict__ si,
                                            const int* __restrict__ sj,
                                            float* __restrict__ ws) {
    __shared__ float azc[64];
    int b = blockIdx.x;
    bool packBlk = b >= NBI + NBJ;
    int pb = b - NBI - NBJ;
    bool isI = packBlk ? (pb < NPKI) : (b < NBI);
    const float* A  = isI ? Ai : Aj;
    const float* ZC = ws + (isI ? W_ZCI : W_ZCJ);
    const float* CS = ws + (isI ? W_CSI : W_CSJ);
    if (threadIdx.x < 2 * KD) {
        int d = threadIdx.x / KD, c = threadIdx.x % KD;
        float acc = 0.f;
#pragma unroll
        for (int a = 0; a < KD; a++)
            acc += A[d * KD + a] * (ZC[a * KD + c] + ZC[640 + a * KD + c]);
        float cs = 0.f;
#pragma unroll
        for (int r = 0; r < 8; r++) cs += CS[(r << 5) + c];
        azc[threadIdx.x] = acc * frcp(cs);
    }
    __syncthreads();
    const float* Z = isI ? Zi : Zj;
    int N = isI ? NI : NJ;
    float z[KD];
    if (!packBlk) {
        int i = (isI ? b : b - NBI) * 256 + threadIdx.x;
        if (i < N) {
            softmax_col(Z, N, i, z);
            float x = 0.f, y = 0.f;
#pragma unroll
            for (int k = 0; k < KD; k++) { x = fmaf(azc[k], z[k], x); y = fmaf(azc[KD + k], z[k], y); }
            float4* Q = (float4*)(ws + (isI ? W_QI : W_QJ));
            if (isI) Q[i] = make_float4(x, y, beta[i], 0.f);
            else     Q[i] = make_float4(x - EPSC, y - EPSC, beta[i], gamma[i]);
        }
    } else {
        int s = (isI ? pb : pb - NPKI) * 256 + threadIdx.x;
        int idx = isI ? si[s] : sj[s];
        softmax_col(Z, N, idx, z);
        float x = 0.f, y = 0.f;
#pragma unroll
        for (int k = 0; k < KD; k++) { x = fmaf(azc[k], z[k], x); y = fmaf(azc[KD + k], z[k], y); }
        float4* QS = (float4*)(ws + (isI ? W_QSI : W_QSJ));
        if (isI) QS[s] = make_float4(x, y, fexp2(beta[idx] * LOG2E), 0.f);
        else     QS[s] = make_float4(x - EPSC, y - EPSC, fexp2(gamma[idx] * LOG2E), 0.f);
    }
}

__device__ __forceinline__ float block_reduce(float v) {
    __shared__ float part[4];
    int lane = threadIdx.x & 63, wv = threadIdx.x >> 6;
#pragma unroll
    for (int o = 32; o > 0; o >>= 1) v += __shfl_down(v, o);
    if (lane == 0) part[wv] = v;
    __syncthreads();
    return part[0] + part[1] + part[2] + part[3];
}

__global__ void __launch_bounds__(256) k_sums(const int* __restrict__ spi,
                                              const int* __restrict__ spj,
                                              float* __restrict__ ws,
                                              float* __restrict__ out) {
    const float4* Qi  = (const float4*)(ws + W_QI);
    const float4* Qj  = (const float4*)(ws + W_QJ);
    const float4* QSI = (const float4*)(ws + W_QSI);
    const float4* QSJ = (const float4*)(ws + W_QSJ);
    int b = blockIdx.x, tid = threadIdx.x;
    float acc = 0.f;
    float scale;
    if (b < NDB) {
        // dense 16 rows x 2048 cols; exp(b+g-d) = e^b * (e^g * 2^(-d*log2e))
        __shared__ float rx[16], ry[16], re[16];
        int r0 = (b >> 1) * 16, c0 = (b & 1) * 2048;
        if (tid < 16) {
            float4 R = QSI[r0 + tid];
            rx[tid] = R.x; ry[tid] = R.y; re[tid] = R.z;
        }
        float cx[8], cy[8], ce[8];
#pragma unroll
        for (int q = 0; q < 8; q++) {
            float4 p = QSJ[c0 + q * 256 + tid];
            cx[q] = p.x; cy[q] = p.y; ce[q] = p.z;
        }
        __syncthreads();
        for (int r = 0; r < 16; r++) {
            float px = rx[r], py = ry[r];
            float accr = 0.f;
#pragma unroll
            for (int q = 0; q < 8; q++) {
                float dx = px - cx[q];
                float dy = py - cy[q];
                float dist = fsqrt(fmaf(dy, dy, dx * dx));
                accr = fmaf(ce[q], fexp2(-LOG2E * dist), accr);
            }
            acc = fmaf(re[r], accr, acc);
        }
        // diagonal pairs (s,s) zeroed in M: the owning block subtracts them
        if (r0 < 4096 && ((r0 >> 11) == (b & 1)) && tid < 16) {
            int s = r0 + tid;
            float4 c = QSJ[s];
            float dx = rx[tid] - c.x, dy = ry[tid] - c.y;
            acc -= re[tid] * c.z * fexp2(-LOG2E * fsqrt(fmaf(dy, dy, dx * dx)));
        }
        scale = -HALF_E2;
    } else {
        int g4 = (b - NDB) * 256 + tid;
        if (g4 < NE / 4) {
            int4 ia = ((const int4*)spi)[g4];
            int4 ja = ((const int4*)spj)[g4];
            float4 a0 = Qi[ia.x], a1 = Qi[ia.y], a2 = Qi[ia.z], a3 = Qi[ia.w];
            float4 b0 = Qj[ja.x], b1 = Qj[ja.y], b2 = Qj[ja.z], b3 = Qj[ja.w];
            float dx, dy;
            dx = a0.x - b0.x; dy = a0.y - b0.y;
            acc += a0.z + b0.z - fsqrt(fmaf(dy, dy, dx * dx));
            dx = a1.x - b1.x; dy = a1.y - b1.y;
            acc += a1.z + b1.z - fsqrt(fmaf(dy, dy, dx * dx));
            dx = a2.x - b2.x; dy = a2.y - b2.y;
            acc += a2.z + b2.z - fsqrt(fmaf(dy, dy, dx * dx));
            dx = a3.x - b3.x; dy = a3.y - b3.y;
            acc += a3.z + b3.z - fsqrt(fmaf(dy, dy, dx * dx));
        }
        scale = 1.f;
    }
    float r = block_reduce(acc);
    if (tid == 0) atomicAdd(&ws[W_PART + (b & 127)], scale * r);

    // completion: last block folds the 128 partials into out[0]
    __shared__ int lastFlag;
    __threadfence();
    if (tid == 0) {
        int old = atomicAdd((int*)&ws[W_CNT], 1);
        lastFlag = (old == NSUMS - 1);
    }
    __syncthreads();
    if (lastFlag) {
        float v = 0.f;
        if (tid < 128)
            v = __hip_atomic_load(&ws[W_PART + tid], __ATOMIC_ACQUIRE,
                                  __HIP_MEMORY_SCOPE_AGENT);
#pragma unroll
        for (int o = 32; o > 0; o >>= 1) v += __shfl_down(v, o);
        __shared__ float w2[4];
        if ((tid & 63) == 0) w2[tid >> 6] = v;
        __syncthreads();
        if (tid == 0) out[0] = w2[0] + w2[1] + w2[2] + w2[3];
    }
}

extern "C" void kernel_launch(void* const* d_in, const int* in_sizes, int n_in,
                              void* d_out, int out_size, void* d_ws, size_t ws_size,
                              hipStream_t stream) {
    const float* beta  = (const float*)d_in[0];
    const float* gamma = (const float*)d_in[1];
    const float* Ai    = (const float*)d_in[2];
    const float* Aj    = (const float*)d_in[3];
    const float* Zi    = (const float*)d_in[4];
    const float* Zj    = (const float*)d_in[5];
    const float* Gi    = (const float*)d_in[6];
    const float* Gj    = (const float*)d_in[7];
    const int* si  = (const int*)d_in[8];
    const int* sj  = (const int*)d_in[9];
    const int* spi = (const int*)d_in[10];
    const int* spj = (const int*)d_in[11];
    float* ws  = (float*)d_ws;
    float* out = (float*)d_out;

    k_init<<<13, 256, 0, stream>>>(ws);
    k_s1<<<NBI + NBJ + NZI + NZJ, 256, 0, stream>>>(Zi, Zj, Gi, Gj, si, sj, ws);
    k_pa<<<NBI + NBJ + NPKI + NPKJ, 256, 0, stream>>>(Zi, Zj, beta, gamma, Ai, Aj, si, sj, ws);
    k_sums<<<NSUMS, 256, 0, stream>>>(spi, spj, ws, out);
}

// Round 6
// 53.954 us; speedup vs baseline: 4.2184x; 4.2184x over previous
//
#include <hip/hip_runtime.h>

#define NI 100000
#define NJ 50000
#define KD 25
#define SI 8192
#define SJ 4096
#define NE 1000000
#define EPSC 1e-6f
#define LOG2E 1.4426950408889634f
#define HALF_E2 3.6945280494653252f   // 0.5 * e * e

#define NBI ((NI + 255) / 256)   // 391
#define NBJ ((NJ + 255) / 256)   // 196
#define NZI (SI / 64)            // 128
#define NZJ (SJ / 64)            // 64
#define NPKI (SI / 256)          // 32 pack blocks (I)
#define NPKJ (SJ / 256)          // 16 pack blocks (J)
#define NDB 1024                 // dense: 512 row-groups x 2 col-halves
#define NSB 1024                 // sparse
#define NSUMS (NDB + NSB)        // 2048

// workspace layout (float offsets)
#define W_CSI 0                  // 8 copies x 32
#define W_CSJ 256
#define W_ZCI 512                // 2 copies x 640
#define W_ZCJ 1792
#define W_PART 3072              // 2048 per-block slots (no atomics)
#define W_QI 8192                // float4[NI]  (x, y, beta, 0)
#define W_QJ (W_QI + 4 * NI)     // float4[NJ]  (x-eps, y-eps, beta, gamma)
#define W_QSI (W_QJ + 4 * NJ)    // float4[SI]  (x, y, e^beta, 0)
#define W_QSJ (W_QSI + 4 * SI)   // float4[SJ]  (x-eps, y-eps, e^gamma, 0)

__device__ __forceinline__ float fexp2(float x) { return __builtin_amdgcn_exp2f(x); }
__device__ __forceinline__ float fsqrt(float x) { return __builtin_amdgcn_sqrtf(x); }
__device__ __forceinline__ float frcp(float x)  { return __builtin_amdgcn_rcpf(x); }
__device__ __forceinline__ float fsig(float g)  { return frcp(1.f + fexp2(-g * LOG2E)); }

__global__ void k_init(float* __restrict__ ws) {
    int t = blockIdx.x * 256 + threadIdx.x;
    if (t < 3072) ws[t] = 0.f;   // CS + ZC accumulators only
}

__device__ __forceinline__ void softmax_col(const float* __restrict__ Z, int N, int i,
                                            float* z) {
    float m = -1e30f;
#pragma unroll
    for (int k = 0; k < KD; k++) { z[k] = Z[k * N + i]; m = fmaxf(m, z[k]); }
    float s = 0.f;
#pragma unroll
    for (int k = 0; k < KD; k++) { z[k] = fexp2((z[k] - m) * LOG2E); s += z[k]; }
    float inv = frcp(s);
#pragma unroll
    for (int k = 0; k < KD; k++) z[k] *= inv;
}

// ---- colsum[k] = sum_i softmax(Z)[k,i] * sigmoid(G[i,k]), 8 spread copies ----
// G window for 256 consecutive nodes is contiguous -> stage via LDS, coalesced.
__device__ void colsum_pass(const float* __restrict__ Z, const float* __restrict__ G,
                            float* __restrict__ colsum, int N, int blk) {
    __shared__ float gs[256 * KD];
    int n0 = blk * 256;
    int lim = (N - n0) * KD;
    if (lim > 256 * KD) lim = 256 * KD;
    for (int t = threadIdx.x; t < lim; t += 256) gs[t] = G[n0 * KD + t];
    __syncthreads();
    int i = n0 + threadIdx.x;
    float z[KD];
    if (i < N) {
        softmax_col(Z, N, i, z);
#pragma unroll
        for (int k = 0; k < KD; k++) z[k] *= fsig(gs[threadIdx.x * KD + k]);
    } else {
#pragma unroll
        for (int k = 0; k < KD; k++) z[k] = 0.f;
    }
    __shared__ float part[KD][4];
    int lane = threadIdx.x & 63, wv = threadIdx.x >> 6;
#pragma unroll
    for (int k = 0; k < KD; k++) {
        float v = z[k];
        for (int o = 32; o > 0; o >>= 1) v += __shfl_down(v, o);
        if (lane == 0) part[k][wv] = v;
    }
    __syncthreads();
    if (threadIdx.x < KD) {
        float v = part[threadIdx.x][0] + part[threadIdx.x][1] +
                  part[threadIdx.x][2] + part[threadIdx.x][3];
        atomicAdd(&colsum[((blk & 7) << 5) + threadIdx.x], v);
    }
}

// ---- ZCraw[a,b] = sum_s z[a,s] * (z[b,s]*sig(g[s,b])), 2 spread copies ----
__device__ void zc_pass(const float* __restrict__ Z, const float* __restrict__ G,
                        const int* __restrict__ samp, float* __restrict__ zcraw,
                        int N, int blk) {
    __shared__ float zb[64][KD + 1];
    __shared__ float zs[64][KD + 1];
    int tid = threadIdx.x;
    if (tid < 64) {
        int idx = samp[blk * 64 + tid];
        float z[KD];
        softmax_col(Z, N, idx, z);
#pragma unroll
        for (int k = 0; k < KD; k++) {
            zb[tid][k] = z[k];
            zs[tid][k] = z[k] * fsig(G[idx * KD + k]);
        }
    }
    __syncthreads();
    for (int p = tid; p < KD * KD; p += 256) {
        int a = p / KD, bb = p % KD;
        float acc = 0.f;
#pragma unroll 8
        for (int s = 0; s < 64; s++) acc += zb[s][a] * zs[s][bb];
        atomicAdd(&zcraw[(blk & 1) * 640 + p], acc);
    }
}

__global__ void __launch_bounds__(256) k_s1(const float* __restrict__ Zi,
                                            const float* __restrict__ Zj,
                                            const float* __restrict__ Gi,
                                            const float* __restrict__ Gj,
                                            const int* __restrict__ si,
                                            const int* __restrict__ sj,
                                            float* __restrict__ ws) {
    int b = blockIdx.x;
    if (b < NBI)                  colsum_pass(Zi, Gi, ws + W_CSI, NI, b);
    else if (b < NBI + NBJ)       colsum_pass(Zj, Gj, ws + W_CSJ, NJ, b - NBI);
    else if (b < NBI + NBJ + NZI) zc_pass(Zi, Gi, si, ws + W_ZCI, NI, b - NBI - NBJ);
    else                          zc_pass(Zj, Gj, sj, ws + W_ZCJ, NJ, b - NBI - NBJ - NZI);
}

// ---- per-node points (Qi/Qj) + sampled packed points (QSI/QSJ) ----
__global__ void __launch_bounds__(256) k_pa(const float* __restrict__ Zi,
                                            const float* __restrict__ Zj,
                                            const float* __restrict__ beta,
                                            const float* __restrict__ gamma,
                                            const float* __restrict__ Ai,
                                            const float* __restrict__ Aj,
                                            const int* __restrict__ si,
                                            const int* __restrict__ sj,
                                            float* __restrict__ ws) {
    __shared__ float azc[64];
    int b = blockIdx.x;
    bool packBlk = b >= NBI + NBJ;
    int pb = b - NBI - NBJ;
    bool isI = packBlk ? (pb < NPKI) : (b < NBI);
    const float* A  = isI ? Ai : Aj;
    const float* ZC = ws + (isI ? W_ZCI : W_ZCJ);
    const float* CS = ws + (isI ? W_CSI : W_CSJ);
    if (threadIdx.x < 2 * KD) {
        int d = threadIdx.x / KD, c = threadIdx.x % KD;
        float acc = 0.f;
#pragma unroll
        for (int a = 0; a < KD; a++)
            acc += A[d * KD + a] * (ZC[a * KD + c] + ZC[640 + a * KD + c]);
        float cs = 0.f;
#pragma unroll
        for (int r = 0; r < 8; r++) cs += CS[(r << 5) + c];
        azc[threadIdx.x] = acc * frcp(cs);
    }
    __syncthreads();
    const float* Z = isI ? Zi : Zj;
    int N = isI ? NI : NJ;
    float z[KD];
    if (!packBlk) {
        int i = (isI ? b : b - NBI) * 256 + threadIdx.x;
        if (i < N) {
            softmax_col(Z, N, i, z);
            float x = 0.f, y = 0.f;
#pragma unroll
            for (int k = 0; k < KD; k++) { x = fmaf(azc[k], z[k], x); y = fmaf(azc[KD + k], z[k], y); }
            float4* Q = (float4*)(ws + (isI ? W_QI : W_QJ));
            if (isI) Q[i] = make_float4(x, y, beta[i], 0.f);
            else     Q[i] = make_float4(x - EPSC, y - EPSC, beta[i], gamma[i]);
        }
    } else {
        int s = (isI ? pb : pb - NPKI) * 256 + threadIdx.x;
        int idx = isI ? si[s] : sj[s];
        softmax_col(Z, N, idx, z);
        float x = 0.f, y = 0.f;
#pragma unroll
        for (int k = 0; k < KD; k++) { x = fmaf(azc[k], z[k], x); y = fmaf(azc[KD + k], z[k], y); }
        float4* QS = (float4*)(ws + (isI ? W_QSI : W_QSJ));
        if (isI) QS[s] = make_float4(x, y, fexp2(beta[idx] * LOG2E), 0.f);
        else     QS[s] = make_float4(x - EPSC, y - EPSC, fexp2(gamma[idx] * LOG2E), 0.f);
    }
}

__device__ __forceinline__ float block_reduce(float v) {
    __shared__ float part[4];
    int lane = threadIdx.x & 63, wv = threadIdx.x >> 6;
#pragma unroll
    for (int o = 32; o > 0; o >>= 1) v += __shfl_down(v, o);
    if (lane == 0) part[wv] = v;
    __syncthreads();
    return part[0] + part[1] + part[2] + part[3];
}

__global__ void __launch_bounds__(256) k_sums(const int* __restrict__ spi,
                                              const int* __restrict__ spj,
                                              float* __restrict__ ws) {
    const float4* Qi  = (const float4*)(ws + W_QI);
    const float4* Qj  = (const float4*)(ws + W_QJ);
    const float4* QSI = (const float4*)(ws + W_QSI);
    const float4* QSJ = (const float4*)(ws + W_QSJ);
    int b = blockIdx.x, tid = threadIdx.x;
    float acc = 0.f;
    float scale;
    if (b < NDB) {
        // dense 16 rows x 2048 cols; exp(b+g-d) = e^b * (e^g * 2^(-d*log2e))
        __shared__ float rx[16], ry[16], re[16];
        int r0 = (b >> 1) * 16, c0 = (b & 1) * 2048;
        if (tid < 16) {
            float4 R = QSI[r0 + tid];
            rx[tid] = R.x; ry[tid] = R.y; re[tid] = R.z;
        }
        float cx[8], cy[8], ce[8];
#pragma unroll
        for (int q = 0; q < 8; q++) {
            float4 p = QSJ[c0 + q * 256 + tid];
            cx[q] = p.x; cy[q] = p.y; ce[q] = p.z;
        }
        __syncthreads();
        for (int r = 0; r < 16; r++) {
            float px = rx[r], py = ry[r];
            float accr = 0.f;
#pragma unroll
            for (int q = 0; q < 8; q++) {
                float dx = px - cx[q];
                float dy = py - cy[q];
                float dist = fsqrt(fmaf(dy, dy, dx * dx));
                accr = fmaf(ce[q], fexp2(-LOG2E * dist), accr);
            }
            acc = fmaf(re[r], accr, acc);
        }
        // diagonal pairs (s,s) zeroed in M: the owning block subtracts them
        if (r0 < 4096 && ((r0 >> 11) == (b & 1)) && tid < 16) {
            int s = r0 + tid;
            float4 c = QSJ[s];
            float dx = rx[tid] - c.x, dy = ry[tid] - c.y;
            acc -= re[tid] * c.z * fexp2(-LOG2E * fsqrt(fmaf(dy, dy, dx * dx)));
        }
        scale = -HALF_E2;
    } else {
        int g4 = (b - NDB) * 256 + tid;
        if (g4 < NE / 4) {
            int4 ia = ((const int4*)spi)[g4];
            int4 ja = ((const int4*)spj)[g4];
            float4 a0 = Qi[ia.x], a1 = Qi[ia.y], a2 = Qi[ia.z], a3 = Qi[ia.w];
            float4 b0 = Qj[ja.x], b1 = Qj[ja.y], b2 = Qj[ja.z], b3 = Qj[ja.w];
            float dx, dy;
            dx = a0.x - b0.x; dy = a0.y - b0.y;
            acc += a0.z + b0.z - fsqrt(fmaf(dy, dy, dx * dx));
            dx = a1.x - b1.x; dy = a1.y - b1.y;
            acc += a1.z + b1.z - fsqrt(fmaf(dy, dy, dx * dx));
            dx = a2.x - b2.x; dy = a2.y - b2.y;
            acc += a2.z + b2.z - fsqrt(fmaf(dy, dy, dx * dx));
            dx = a3.x - b3.x; dy = a3.y - b3.y;
            acc += a3.z + b3.z - fsqrt(fmaf(dy, dy, dx * dx));
        }
        scale = 1.f;
    }
    float r = block_reduce(acc);
    if (tid == 0) ws[W_PART + b] = scale * r;   // private slot, plain store
}

__global__ void __launch_bounds__(256) k_fin(const float* __restrict__ ws,
                                             float* __restrict__ out) {
    int tid = threadIdx.x;
    float v = 0.f;
#pragma unroll
    for (int q = 0; q < NSUMS / 256; q++) v += ws[W_PART + q * 256 + tid];
    __shared__ float part[4];
    int lane = tid & 63, wv = tid >> 6;
#pragma unroll
    for (int o = 32; o > 0; o >>= 1) v += __shfl_down(v, o);
    if (lane == 0) part[wv] = v;
    __syncthreads();
    if (tid == 0) out[0] = part[0] + part[1] + part[2] + part[3];
}

extern "C" void kernel_launch(void* const* d_in, const int* in_sizes, int n_in,
                              void* d_out, int out_size, void* d_ws, size_t ws_size,
                              hipStream_t stream) {
    const float* beta  = (const float*)d_in[0];
    const float* gamma = (const float*)d_in[1];
    const float* Ai    = (const float*)d_in[2];
    const float* Aj    = (const float*)d_in[3];
    const float* Zi    = (const float*)d_in[4];
    const float* Zj    = (const float*)d_in[5];
    const float* Gi    = (const float*)d_in[6];
    const float* Gj    = (const float*)d_in[7];
    const int* si  = (const int*)d_in[8];
    const int* sj  = (const int*)d_in[9];
    const int* spi = (const int*)d_in[10];
    const int* spj = (const int*)d_in[11];
    float* ws  = (float*)d_ws;
    float* out = (float*)d_out;

    k_init<<<12, 256, 0, stream>>>(ws);
    k_s1<<<NBI + NBJ + NZI + NZJ, 256, 0, stream>>>(Zi, Zj, Gi, Gj, si, sj, ws);
    k_pa<<<NBI + NBJ + NPKI + NPKJ, 256, 0, stream>>>(Zi, Zj, beta, gamma, Ai, Aj, si, sj, ws);
    k_sums<<<NSUMS, 256, 0, stream>>>(spi, spj, ws);
    k_fin<<<1, 256, 0, stream>>>(ws, out);
}